// Round 2
// baseline (159.291 us; speedup 1.0000x reference)
//
#include <hip/hip_runtime.h>

#define N_REAL 12
#define BATCH  4
#define CH     3
#define HH     256
#define WW     256
#define KK     4
#define TILE   32
#define HALO   35                 // TILE + KK - 1
#define HSTR   36                 // padded LDS row stride (dwords) -> 16B-aligned rows
#define PLANE  (HALO * HSTR)      // 1260 dwords; 1260*4 = 5040 B = 16B multiple
#define NTHR   256
#define HW     (HH * WW)
#define NSTAGE 3675               // 3 * 35 * 35 real elements to stage

__device__ __forceinline__ float sigmoidf(float x) {
    float e = __builtin_amdgcn_exp2f(x * -1.44269504088896340736f);
    return __builtin_amdgcn_rcpf(1.0f + e);
}

__global__ __launch_bounds__(NTHR, 6)
void reverb_fused(const float* __restrict__ states,
                  const float* __restrict__ weights,
                  const float* __restrict__ bias,
                  float*       __restrict__ out)
{
    __shared__ float sIn[CH * PLANE];          // 15120 B

    const int v   = blockIdx.z;                // destination node 0..11
    const int b   = blockIdx.y;                // batch
    const int bx  = blockIdx.x;                // tile-pair 0..31
    const int tid = threadIdx.x;
    const int y   = tid >> 3;                  // 0..31
    const int x0  = (tid & 7) << 2;            // 0,4,...,28

    // ---- analytic incoming edge list (fixed ring+skip topology) ----
    int us[4], es[4];
    us[0] = (v + 11) % 12;  es[0] = us[0] * 3 + 0;   // d=1
    us[1] = (v + 10) % 12;  es[1] = us[1] * 3 + 1;   // d=2
    us[2] = (v +  9) % 12;  es[2] = us[2] * 3 + 2;   // d=3
    us[3] = 12;             es[3] = 36;              // driver -> node 0
    const int deg = (v == 0) ? 4 : 3;

    // ---- LDS write offsets: tile/edge-invariant, build once ----
    int loff[15];
    int pci[15], piy[15], pix[15];
    #pragma unroll
    for (int k = 0; k < 15; ++k) {
        const int idx = tid + k * NTHR;        // 0..3839 (valid < 3675)
        const int ci  = idx / 1225;
        const int r   = idx - ci * 1225;
        const int iy  = r / 35;
        const int ix  = r - iy * 35;
        pci[k] = ci; piy[k] = iy; pix[k] = ix;
        loff[k] = ci * PLANE + iy * HSTR + ix;
    }

    for (int t = 2 * bx; t <= 2 * bx + 1; ++t) {
        const int oy0 = (t >> 3) * TILE;
        const int ox0 = (t & 7) * TILE;

        // ---- per-tile global gather offsets (-1 == zero-pad) ----
        int goff[15];
        #pragma unroll
        for (int k = 0; k < 15; ++k) {
            const int gy = oy0 + piy[k] - 1;   // SAME pad: lo=1, hi=2
            const int gx = ox0 + pix[k] - 1;
            const bool ok = ((unsigned)gy < HH) & ((unsigned)gx < WW);
            goff[k] = ok ? ((pci[k] << 16) + (gy << 8) + gx) : -1;
        }

        float acc[CH][4];
        #pragma unroll
        for (int co = 0; co < CH; ++co)
            #pragma unroll
            for (int p = 0; p < 4; ++p) acc[co][p] = 0.0f;
        float bsum[CH] = {0.0f, 0.0f, 0.0f};

        for (int ei = 0; ei < deg; ++ei) {
            const int u = us[ei];
            const int e = es[ei];
            const float* __restrict__ src =
                states + (size_t)(u * (BATCH * CH) + b * CH) * HW;

            __syncthreads();                   // previous readers done
            #pragma unroll
            for (int k = 0; k < 14; ++k) {     // all 14 full chunks valid
                const int g = goff[k];
                float val = 0.0f;
                if (g >= 0) val = sigmoidf(src[g]);
                sIn[loff[k]] = val;
            }
            if (tid < NSTAGE - 14 * NTHR) {    // tail: 91 threads
                const int g = goff[14];
                float val = 0.0f;
                if (g >= 0) val = sigmoidf(src[g]);
                sIn[loff[14]] = val;
            }
            __syncthreads();

            // uniform (scalar) weight/bias reads straight from global
            const float* __restrict__ wbase = weights + e * (CH * CH * KK * KK);
            bsum[0] += bias[e * CH + 0];
            bsum[1] += bias[e * CH + 1];
            bsum[2] += bias[e * CH + 2];

            #pragma unroll
            for (int ci = 0; ci < CH; ++ci) {
                #pragma unroll
                for (int ky = 0; ky < KK; ++ky) {
                    const float* rp = &sIn[ci * PLANE + (y + ky) * HSTR + x0];
                    const float4 lo = *(const float4*)rp;        // 16B aligned
                    const float4 hi = *(const float4*)(rp + 4);  // 16B aligned
                    const float vv[7] = {lo.x, lo.y, lo.z, lo.w, hi.x, hi.y, hi.z};
                    #pragma unroll
                    for (int co = 0; co < CH; ++co) {
                        const float4 wv =
                            *(const float4*)(wbase + ((co * CH + ci) * KK + ky) * KK);
                        #pragma unroll
                        for (int p = 0; p < 4; ++p) {
                            acc[co][p] = fmaf(wv.x, vv[p + 0], acc[co][p]);
                            acc[co][p] = fmaf(wv.y, vv[p + 1], acc[co][p]);
                            acc[co][p] = fmaf(wv.z, vv[p + 2], acc[co][p]);
                            acc[co][p] = fmaf(wv.w, vv[p + 3], acc[co][p]);
                        }
                    }
                }
            }
        }

        const float inv = 1.0f / (float)deg;
        const size_t obase = (size_t)(v * BATCH + b) * CH * HW;
        #pragma unroll
        for (int co = 0; co < CH; ++co) {
            float4 o;
            o.x = (acc[co][0] + bsum[co]) * inv;
            o.y = (acc[co][1] + bsum[co]) * inv;
            o.z = (acc[co][2] + bsum[co]) * inv;
            o.w = (acc[co][3] + bsum[co]) * inv;
            *(float4*)&out[obase + (size_t)co * HW +
                           (size_t)(oy0 + y) * WW + ox0 + x0] = o;
        }
    }
}

extern "C" void kernel_launch(void* const* d_in, const int* in_sizes, int n_in,
                              void* d_out, int out_size, void* d_ws, size_t ws_size,
                              hipStream_t stream)
{
    const float* states  = (const float*)d_in[0];
    const float* weights = (const float*)d_in[1];
    const float* bias    = (const float*)d_in[2];
    float*       out     = (float*)d_out;

    dim3 grid(32, BATCH, N_REAL);              // 1536 blocks = 6/CU, fully resident
    reverb_fused<<<grid, NTHR, 0, stream>>>(states, weights, bias, out);
}

// Round 3
// 68.134 us; speedup vs baseline: 2.3379x; 2.3379x over previous
//
#include <hip/hip_runtime.h>

#define N_REAL 12
#define BATCH  4
#define CH     3
#define HH     256
#define WW     256
#define KK     4
#define TILE   32
#define HALO   35                 // TILE + KK - 1; odd stride -> conflict-free scalar LDS reads
#define NTHR   256
#define HW     (HH * WW)
#define HH2    (HALO * HALO)      // 1225
#define NSTAGE (CH * HH2)         // 3675

__device__ __forceinline__ float sigmoidf(float x) {
    float e = __builtin_amdgcn_exp2f(x * -1.44269504088896340736f);
    return __builtin_amdgcn_rcpf(1.0f + e);
}

__global__ __launch_bounds__(NTHR, 4)
void reverb_fused(const float* __restrict__ states,
                  const float* __restrict__ weights,
                  const float* __restrict__ bias,
                  float*       __restrict__ out)
{
    // linear layout: LDS offset == staging index (no loff math); slots >= NSTAGE
    // absorb the k=14 invalid-lane dummy writes.
    __shared__ float sIn[15 * NTHR];               // 15360 B

    const int v   = blockIdx.z;                    // destination node 0..11
    const int b   = blockIdx.y;                    // batch
    const int t   = blockIdx.x;                    // tile 0..63
    const int oy0 = (t >> 3) * TILE;
    const int ox0 = (t & 7) * TILE;
    const int tid = threadIdx.x;
    const int y   = tid >> 3;                      // 0..31
    const int x0  = (tid & 7) << 2;                // 0,4,...,28

    const int deg = (v == 0) ? 4 : 3;

    // ---- per-tile gather offsets: computed ONCE (15 VGPRs, -1 == zero-pad) ----
    int goff[15];
    #pragma unroll
    for (int k = 0; k < 15; ++k) {
        const int idx = tid + k * NTHR;
        const int ci  = idx / HH2;                 // magic-mul, once per tile
        const int r   = idx - ci * HH2;
        const int iy  = r / HALO;
        const int ix  = r - iy * HALO;
        const int gy  = oy0 + iy - 1;              // SAME pad: lo=1, hi=2
        const int gx  = ox0 + ix - 1;
        const bool ok = (idx < NSTAGE) && ((unsigned)gy < HH) && ((unsigned)gx < WW);
        goff[k] = ok ? (ci * HW + gy * WW + gx) : -1;
    }

    float acc[CH][4];
    #pragma unroll
    for (int co = 0; co < CH; ++co)
        #pragma unroll
        for (int p = 0; p < 4; ++p) acc[co][p] = 0.0f;
    float bsum[CH] = {0.0f, 0.0f, 0.0f};

    // ---- prefetch edge 0 (u = (v+11)%12) into registers ----
    float pre[15];
    {
        int u0 = v + 11; if (u0 >= 12) u0 -= 12;
        const float* __restrict__ src = states + (size_t)(u0 * (BATCH * CH) + b * CH) * HW;
        #pragma unroll
        for (int k = 0; k < 15; ++k)
            pre[k] = (goff[k] >= 0) ? src[goff[k]] : 0.0f;
    }

    for (int ei = 0; ei < deg; ++ei) {
        // current edge index e (uniform: derived from blockIdx + loop counter)
        int uc = v + 11 - ei; if (uc >= 12) uc -= 12;
        const int e = (ei == 3) ? 36 : (uc * 3 + ei);

        __syncthreads();                           // prev edge's readers done
        #pragma unroll
        for (int k = 0; k < 15; ++k)
            sIn[tid + k * NTHR] = (goff[k] >= 0) ? sigmoidf(pre[k]) : 0.0f;
        __syncthreads();

        // ---- prefetch next edge during this edge's compute ----
        if (ei + 1 < deg) {
            int un = v + 10 - ei; if (un >= 12) un -= 12;
            if (ei + 1 == 3) un = 12;              // driver node
            const float* __restrict__ srcn =
                states + (size_t)(un * (BATCH * CH) + b * CH) * HW;
            #pragma unroll
            for (int k = 0; k < 15; ++k)
                pre[k] = (goff[k] >= 0) ? srcn[goff[k]] : 0.0f;
        }

        // uniform weight/bias reads (scalarize to s_load, SGPR operands in v_fma)
        bsum[0] += bias[e * CH + 0];
        bsum[1] += bias[e * CH + 1];
        bsum[2] += bias[e * CH + 2];
        const float* __restrict__ wbase = weights + e * (CH * CH * KK * KK);

        #pragma unroll
        for (int ci = 0; ci < CH; ++ci) {
            #pragma unroll
            for (int ky = 0; ky < KK; ++ky) {
                const float* rp = &sIn[ci * HH2 + (y + ky) * HALO + x0];
                float vv[7];
                #pragma unroll
                for (int j = 0; j < 7; ++j) vv[j] = rp[j];   // stride-35: 2-way max (free)
                #pragma unroll
                for (int kx = 0; kx < KK; ++kx) {
                    #pragma unroll
                    for (int co = 0; co < CH; ++co) {
                        const float w = wbase[((co * CH + ci) * KK + ky) * KK + kx];
                        #pragma unroll
                        for (int p = 0; p < 4; ++p)
                            acc[co][p] = fmaf(w, vv[p + kx], acc[co][p]);
                    }
                }
            }
        }
    }

    const float inv = 1.0f / (float)deg;
    const size_t obase = (size_t)(v * BATCH + b) * CH * HW;
    #pragma unroll
    for (int co = 0; co < CH; ++co) {
        float4 o;
        o.x = (acc[co][0] + bsum[co]) * inv;
        o.y = (acc[co][1] + bsum[co]) * inv;
        o.z = (acc[co][2] + bsum[co]) * inv;
        o.w = (acc[co][3] + bsum[co]) * inv;
        *(float4*)&out[obase + (size_t)co * HW +
                       (size_t)(oy0 + y) * WW + ox0 + x0] = o;
    }
}

extern "C" void kernel_launch(void* const* d_in, const int* in_sizes, int n_in,
                              void* d_out, int out_size, void* d_ws, size_t ws_size,
                              hipStream_t stream)
{
    const float* states  = (const float*)d_in[0];
    const float* weights = (const float*)d_in[1];
    const float* bias    = (const float*)d_in[2];
    float*       out     = (float*)d_out;

    dim3 grid(HH / TILE * (WW / TILE), BATCH, N_REAL);   // 64 x 4 x 12 = 3072 blocks
    reverb_fused<<<grid, NTHR, 0, stream>>>(states, weights, bias, out);
}